// Round 4
// baseline (126.459 us; speedup 1.0000x reference)
//
#include <hip/hip_runtime.h>
#include <math.h>

// Problem constants (from reference): B=128, C=3, H=256, W=256, fp32.
#define BATCH 128
#define CHAN  3
#define IMH   256
#define IMW   256
#define NXCD  8
#define TW    16   // output tile width  (per block)
#define TH    16   // output tile height (per block)

// LDS staged tile: bbox (<=40x41) + 1-cell halo on every side.
// Stride 43 (odd) keeps scattered ds_reads bank-benign.
#define BH_PAD 42
#define BW_PAD 43

// ---------------------------------------------------------------------------
// Kernel 1: per-batch affine matrix theta (2x3) -> ws[6*b .. 6*b+5]
// ---------------------------------------------------------------------------
__global__ void theta_kernel(const float* __restrict__ rot,
                             const float* __restrict__ trans,
                             const float* __restrict__ scale,
                             const float* __restrict__ shear,
                             float* __restrict__ theta) {
    int b = threadIdx.x;
    if (b >= BATCH) return;
    float r   = rot[b];
    float s   = scale[b];
    float c   = cosf(r);
    float sn  = sinf(r);
    float shx = shear[2 * b + 0];
    float shy = shear[2 * b + 1];
    theta[6 * b + 0] = s * (c - sn * shy);        // a00
    theta[6 * b + 1] = s * (c * shx - sn);        // a01
    theta[6 * b + 2] = trans[2 * b + 0];          // tx
    theta[6 * b + 3] = s * (sn + c * shy);        // a10
    theta[6 * b + 4] = s * (sn * shx + c);        // a11
    theta[6 * b + 5] = trans[2 * b + 1];          // ty
}

// ---------------------------------------------------------------------------
// Kernel 2: affine grid + bilinear sample with LDS-staged input footprint.
// Block = 256 threads = one 16x16 output tile. The affine image of the tile
// is a rotated square whose bbox (~28x28 here) we stage densely into LDS with
// coalesced loads; the 4-corner bilinear gather then runs from LDS as
// ds_read2_b32 pairs instead of ~30-line-split global gathers.
// Halo: +1 cell on every side. Reference semantics guarantee any tap landing
// in the halo has zero weight (x0<x_lo only possible via clamping => invalid),
// and halo cells are explicitly zero-filled, so no NaN can leak through 0*x.
// ---------------------------------------------------------------------------
__global__ __launch_bounds__(256) void affine_sample_kernel(
        const float* __restrict__ img,
        const float* __restrict__ theta,
        float* __restrict__ out) {
    __shared__ float tile[CHAN][BH_PAD][BW_PAD];   // 21,672 B

    const int NBLK = BATCH * (IMH / TH) * (IMW / TW);   // 32768
    const int p = blockIdx.x;
    const int L = (p & (NXCD - 1)) * (NBLK / NXCD) + (p >> 3);  // XCD-chunked

    const int b    = L >> 8;          // 256 tiles per image
    const int tl   = L & 255;
    const int ty   = tl >> 4;
    const int tx   = tl & 15;
    const int w0   = tx * TW;
    const int h0   = ty * TH;

    const float* th = theta + 6 * b;
    const float a00 = th[0], a01 = th[1], txx = th[2];
    const float a10 = th[3], a11 = th[4], tyy = th[5];

    // --- block-uniform bbox of the input footprint (map is affine) ---------
    // dix/dw = a00, dix/dh = a01, diy/dw = a10, diy/dh = a11  (exact)
    const float wc = (float)w0 + 7.5f;
    const float hc = (float)h0 + 7.5f;
    const float gxc = 2.0f * (wc + 0.5f) / (float)IMW - 1.0f;
    const float gyc = 2.0f * (hc + 0.5f) / (float)IMH - 1.0f;
    const float ixc = ((a00 * gxc + a01 * gyc + txx + 1.0f) * (float)IMW - 1.0f) * 0.5f;
    const float iyc = ((a10 * gxc + a11 * gyc + tyy + 1.0f) * (float)IMH - 1.0f) * 0.5f;
    const float half_x = 7.5f * (fabsf(a00) + fabsf(a01));
    const float half_y = 7.5f * (fabsf(a10) + fabsf(a11));

    const int x_lo = min(max((int)floorf(ixc - half_x), 0), IMW - 1);
    const int x_hi = min(max((int)floorf(ixc + half_x) + 1, 0), IMW - 1);
    const int y_lo = min(max((int)floorf(iyc - half_y), 0), IMH - 1);
    const int y_hi = min(max((int)floorf(iyc + half_y) + 1, 0), IMH - 1);

    const int plane = IMH * IMW;
    const int t = threadIdx.x;
    const int wq = w0 + (t & (TW - 1));
    const int hq = h0 + (t >> 4);

    // --- per-thread sample coordinates (reference math, unchanged) ---------
    const float gx = 2.0f * ((float)wq + 0.5f) / (float)IMW - 1.0f;
    const float gy = 2.0f * ((float)hq + 0.5f) / (float)IMH - 1.0f;
    const float gridx = a00 * gx + a01 * gy + txx;
    const float gridy = a10 * gx + a11 * gy + tyy;
    const float ix = ((gridx + 1.0f) * (float)IMW - 1.0f) * 0.5f;
    const float iy = ((gridy + 1.0f) * (float)IMH - 1.0f) * 0.5f;

    const float x0f = floorf(ix);
    const float y0f = floorf(iy);
    const float x1f = x0f + 1.0f;
    const float y1f = y0f + 1.0f;

    const float wx1 = ix - x0f;
    const float wx0 = 1.0f - wx1;
    const float wy1 = iy - y0f;
    const float wy0 = 1.0f - wy1;

    const bool vx0 = (x0f >= 0.0f) & (x0f <= (float)(IMW - 1));
    const bool vx1 = (x1f >= 0.0f) & (x1f <= (float)(IMW - 1));
    const bool vy0 = (y0f >= 0.0f) & (y0f <= (float)(IMH - 1));
    const bool vy1 = (y1f >= 0.0f) & (y1f <= (float)(IMH - 1));

    const float w00 = (vx0 && vy0) ? (wx0 * wy0) : 0.0f;
    const float w10 = (vx1 && vy0) ? (wx1 * wy0) : 0.0f;
    const float w01 = (vx0 && vy1) ? (wx0 * wy1) : 0.0f;
    const float w11 = (vx1 && vy1) ? (wx1 * wy1) : 0.0f;

    const int x0 = (int)x0f;   // may be far out of range; weights cover it
    const int y0 = (int)y0f;

    const int obase = (b * CHAN) * plane + hq * IMW + wq;
    const float* ibase = img + (size_t)(b * CHAN) * plane;

    // --- staged path iff bbox fits LDS (with halo). Block-uniform branch. --
    if ((x_hi - x_lo) <= BW_PAD - 3 && (y_hi - y_lo) <= BH_PAD - 3) {
        // stage: rows y_lo-1 .. y_hi+1, cols x_lo-1 .. x_hi+1 (zeros outside img)
        const int ny = (y_hi - y_lo) + 3;   // <= 42
        const int nx = (x_hi - x_lo) + 3;   // <= 43
        const int lane = t & 63;
        const int quad = t >> 6;
        const int xg = x_lo - 1 + lane;
        const bool xin = (lane < nx) & ((unsigned)xg < (unsigned)IMW);
#pragma unroll
        for (int c = 0; c < CHAN; ++c) {
            const float* src = ibase + c * plane;
            for (int dy = quad; dy < ny; dy += 4) {
                const int yg = y_lo - 1 + dy;
                float v = 0.0f;
                if (xin & ((unsigned)yg < (unsigned)IMH))
                    v = src[yg * IMW + xg];
                if (lane < nx) tile[c][dy][lane] = v;
            }
        }
        __syncthreads();

        // gather from LDS; +1 shift = halo. Clamp keeps indices in-array;
        // any clamped/halo tap provably has zero weight.
        const int rx = min(max(x0 - x_lo + 1, 0), BW_PAD - 2);
        const int ry = min(max(y0 - y_lo + 1, 0), BH_PAD - 2);
#pragma unroll
        for (int c = 0; c < CHAN; ++c) {
            const float* tp = &tile[c][ry][rx];
            const float p00 = tp[0];
            const float p10 = tp[1];
            const float p01 = tp[BW_PAD];
            const float p11 = tp[BW_PAD + 1];
            float v = w00 * p00 + w10 * p10 + w01 * p01 + w11 * p11;
            __builtin_nontemporal_store(v, &out[obase + c * plane]);
        }
    } else {
        // fallback: direct global gathers (rare: huge shear/scale)
        const int x0c = min(max(x0, 0), IMW - 1);
        const int x1c = min(max(x0 + 1, 0), IMW - 1);
        const int y0c = min(max(y0, 0), IMH - 1);
        const int y1c = min(max(y0 + 1, 0), IMH - 1);
        const int i00 = y0c * IMW + x0c;
        const int i10 = y0c * IMW + x1c;
        const int i01 = y1c * IMW + x0c;
        const int i11 = y1c * IMW + x1c;
#pragma unroll
        for (int c = 0; c < CHAN; ++c) {
            const float* p2 = ibase + c * plane;
            float v = w00 * p2[i00] + w10 * p2[i10] + w01 * p2[i01] + w11 * p2[i11];
            __builtin_nontemporal_store(v, &out[obase + c * plane]);
        }
    }
}

extern "C" void kernel_launch(void* const* d_in, const int* in_sizes, int n_in,
                              void* d_out, int out_size, void* d_ws, size_t ws_size,
                              hipStream_t stream) {
    const float* img   = (const float*)d_in[0];
    const float* rot   = (const float*)d_in[1];
    const float* trans = (const float*)d_in[2];
    const float* scale = (const float*)d_in[3];
    const float* shear = (const float*)d_in[4];
    float* out   = (float*)d_out;
    float* theta = (float*)d_ws;   // 128 * 6 floats = 3 KB scratch

    theta_kernel<<<1, BATCH, 0, stream>>>(rot, trans, scale, shear, theta);

    const int nblocks = BATCH * (IMH / TH) * (IMW / TW);   // 32768
    affine_sample_kernel<<<nblocks, 256, 0, stream>>>(img, theta, out);
}

// Round 5
// 55.471 us; speedup vs baseline: 2.2797x; 2.2797x over previous
//
#include <hip/hip_runtime.h>
#include <math.h>

// Problem constants (from reference): B=128, C=3, H=256, W=256, fp32.
#define BATCH 128
#define CHAN  3
#define IMH   256
#define IMW   256
#define NXCD  8
#define TW    16   // output tile width  (per block)
#define TH    16   // output tile height (per block)

// LDS staged tile: bbox + 1-cell halo on every side. Stride 43 (odd).
#define BH_PAD 42
#define BW_PAD 43

// ---------------------------------------------------------------------------
// Kernel 1: per-batch affine matrix theta (2x3) -> ws[6*b .. 6*b+5]
// ---------------------------------------------------------------------------
__global__ void theta_kernel(const float* __restrict__ rot,
                             const float* __restrict__ trans,
                             const float* __restrict__ scale,
                             const float* __restrict__ shear,
                             float* __restrict__ theta) {
    int b = threadIdx.x;
    if (b >= BATCH) return;
    float r   = rot[b];
    float s   = scale[b];
    float c   = cosf(r);
    float sn  = sinf(r);
    float shx = shear[2 * b + 0];
    float shy = shear[2 * b + 1];
    theta[6 * b + 0] = s * (c - sn * shy);        // a00
    theta[6 * b + 1] = s * (c * shx - sn);        // a01
    theta[6 * b + 2] = trans[2 * b + 0];          // tx
    theta[6 * b + 3] = s * (sn + c * shy);        // a10
    theta[6 * b + 4] = s * (sn * shx + c);        // a11
    theta[6 * b + 5] = trans[2 * b + 1];          // ty
}

// ---------------------------------------------------------------------------
// Kernel 2: affine grid + bilinear sample with LDS-staged input footprint.
// Block = 256 threads = one 16x16 output tile.
// Stager: 256 threads mapped 32 wide x 8 tall per round; channel-inner so
// address+validity math is shared across the 3 channels. Branchless OOB:
// clamped address + zero-select. Typical cost: 4 rounds x (3 loads + 3
// ds_writes), all 64 lanes of every wave active, row-dense -> ~190 L1 line
// requests per block vs ~900 for the direct-gather path.
// ---------------------------------------------------------------------------
__global__ __launch_bounds__(256) void affine_sample_kernel(
        const float* __restrict__ img,
        const float* __restrict__ theta,
        float* __restrict__ out) {
    __shared__ float tile[CHAN][BH_PAD][BW_PAD];   // 21,672 B

    const int NBLK = BATCH * (IMH / TH) * (IMW / TW);   // 32768
    const int p = blockIdx.x;
    const int L = (p & (NXCD - 1)) * (NBLK / NXCD) + (p >> 3);  // XCD-chunked

    const int b    = L >> 8;          // 256 tiles per image
    const int tl   = L & 255;
    const int ty   = tl >> 4;
    const int tx   = tl & 15;
    const int w0   = tx * TW;
    const int h0   = ty * TH;

    const float* th = theta + 6 * b;
    const float a00 = th[0], a01 = th[1], txx = th[2];
    const float a10 = th[3], a11 = th[4], tyy = th[5];

    // --- block-uniform bbox of the input footprint (map is affine) ---------
    const float wc = (float)w0 + 7.5f;
    const float hc = (float)h0 + 7.5f;
    const float gxc = 2.0f * (wc + 0.5f) / (float)IMW - 1.0f;
    const float gyc = 2.0f * (hc + 0.5f) / (float)IMH - 1.0f;
    const float ixc = ((a00 * gxc + a01 * gyc + txx + 1.0f) * (float)IMW - 1.0f) * 0.5f;
    const float iyc = ((a10 * gxc + a11 * gyc + tyy + 1.0f) * (float)IMH - 1.0f) * 0.5f;
    const float half_x = 7.5f * (fabsf(a00) + fabsf(a01));
    const float half_y = 7.5f * (fabsf(a10) + fabsf(a11));

    const int x_lo = min(max((int)floorf(ixc - half_x), 0), IMW - 1);
    const int x_hi = min(max((int)floorf(ixc + half_x) + 1, 0), IMW - 1);
    const int y_lo = min(max((int)floorf(iyc - half_y), 0), IMH - 1);
    const int y_hi = min(max((int)floorf(iyc + half_y) + 1, 0), IMH - 1);

    const int nx = (x_hi - x_lo) + 3;   // staged cols (incl. halo)
    const int ny = (y_hi - y_lo) + 3;   // staged rows (incl. halo)

    const int plane = IMH * IMW;
    const int t = threadIdx.x;
    const int wq = w0 + (t & (TW - 1));
    const int hq = h0 + (t >> 4);

    // --- per-thread sample coordinates (reference math, unchanged) ---------
    const float gx = 2.0f * ((float)wq + 0.5f) / (float)IMW - 1.0f;
    const float gy = 2.0f * ((float)hq + 0.5f) / (float)IMH - 1.0f;
    const float gridx = a00 * gx + a01 * gy + txx;
    const float gridy = a10 * gx + a11 * gy + tyy;
    const float ix = ((gridx + 1.0f) * (float)IMW - 1.0f) * 0.5f;
    const float iy = ((gridy + 1.0f) * (float)IMH - 1.0f) * 0.5f;

    const float x0f = floorf(ix);
    const float y0f = floorf(iy);
    const float x1f = x0f + 1.0f;
    const float y1f = y0f + 1.0f;

    const float wx1 = ix - x0f;
    const float wx0 = 1.0f - wx1;
    const float wy1 = iy - y0f;
    const float wy0 = 1.0f - wy1;

    const bool vx0 = (x0f >= 0.0f) & (x0f <= (float)(IMW - 1));
    const bool vx1 = (x1f >= 0.0f) & (x1f <= (float)(IMW - 1));
    const bool vy0 = (y0f >= 0.0f) & (y0f <= (float)(IMH - 1));
    const bool vy1 = (y1f >= 0.0f) & (y1f <= (float)(IMH - 1));

    const float w00 = (vx0 && vy0) ? (wx0 * wy0) : 0.0f;
    const float w10 = (vx1 && vy0) ? (wx1 * wy0) : 0.0f;
    const float w01 = (vx0 && vy1) ? (wx0 * wy1) : 0.0f;
    const float w11 = (vx1 && vy1) ? (wx1 * wy1) : 0.0f;

    const int x0 = (int)x0f;   // may be far out of range; weights cover it
    const int y0 = (int)y0f;

    const int obase = (b * CHAN) * plane + hq * IMW + wq;
    const float* ibase = img + (size_t)(b * CHAN) * plane;

    // --- staged path iff bbox (+halo) fits LDS. Block-uniform branch. ------
    if (nx <= BW_PAD && ny <= BH_PAD) {
        // Stage rows y_lo-1 .. y_lo-1+ny-1, cols x_lo-1 .. x_lo-1+nx-1,
        // zero outside the image. Lane map: 32 wide x 8 tall per round.
        const int lx  = t & 31;        // 0..31 column within sweep
        const int lyo = t >> 5;        // 0..7  row within round
        const int nrounds = (ny + 7) >> 3;          // <= 6 (typ. 4)
        const int nsweeps = (nx + 31) >> 5;         // 1 or 2

        for (int s = 0; s < nsweeps; ++s) {
            const int col = (s << 5) + lx;          // tile column
            const int xg  = x_lo - 1 + col;         // global x
            const bool xin = (col < nx) & ((unsigned)xg < (unsigned)IMW);
            const int xgc = min(max(xg, 0), IMW - 1);
            const bool wok = (col < nx);
            for (int r = 0; r < nrounds; ++r) {
                const int dy = (r << 3) + lyo;      // tile row
                const int yg = y_lo - 1 + dy;
                const bool vin = xin & ((unsigned)yg < (unsigned)IMH);
                const int ygc = min(max(yg, 0), IMH - 1);
                const int idx = ygc * IMW + xgc;
                const bool wr = wok & (dy < ny);
                float v0 = ibase[idx];
                float v1 = ibase[idx + plane];
                float v2 = ibase[idx + 2 * plane];
                v0 = vin ? v0 : 0.0f;
                v1 = vin ? v1 : 0.0f;
                v2 = vin ? v2 : 0.0f;
                if (wr) {
                    tile[0][dy][col] = v0;
                    tile[1][dy][col] = v1;
                    tile[2][dy][col] = v2;
                }
            }
        }
        __syncthreads();

        // Gather from LDS; +1 shift = halo. Clamp to the WRITTEN region
        // (nx-2 / ny-2) so a zero-weight tap can never read uninitialized LDS.
        const int rx = min(max(x0 - x_lo + 1, 0), nx - 2);
        const int ry = min(max(y0 - y_lo + 1, 0), ny - 2);
#pragma unroll
        for (int c = 0; c < CHAN; ++c) {
            const float* tp = &tile[c][ry][rx];
            const float p00 = tp[0];
            const float p10 = tp[1];
            const float p01 = tp[BW_PAD];
            const float p11 = tp[BW_PAD + 1];
            float v = w00 * p00 + w10 * p10 + w01 * p01 + w11 * p11;
            __builtin_nontemporal_store(v, &out[obase + c * plane]);
        }
    } else {
        // fallback: direct global gathers (rare: huge shear/rotation extremes)
        const int x0c = min(max(x0, 0), IMW - 1);
        const int x1c = min(max(x0 + 1, 0), IMW - 1);
        const int y0c = min(max(y0, 0), IMH - 1);
        const int y1c = min(max(y0 + 1, 0), IMH - 1);
        const int i00 = y0c * IMW + x0c;
        const int i10 = y0c * IMW + x1c;
        const int i01 = y1c * IMW + x0c;
        const int i11 = y1c * IMW + x1c;
#pragma unroll
        for (int c = 0; c < CHAN; ++c) {
            const float* p2 = ibase + c * plane;
            float v = w00 * p2[i00] + w10 * p2[i10] + w01 * p2[i01] + w11 * p2[i11];
            __builtin_nontemporal_store(v, &out[obase + c * plane]);
        }
    }
}

extern "C" void kernel_launch(void* const* d_in, const int* in_sizes, int n_in,
                              void* d_out, int out_size, void* d_ws, size_t ws_size,
                              hipStream_t stream) {
    const float* img   = (const float*)d_in[0];
    const float* rot   = (const float*)d_in[1];
    const float* trans = (const float*)d_in[2];
    const float* scale = (const float*)d_in[3];
    const float* shear = (const float*)d_in[4];
    float* out   = (float*)d_out;
    float* theta = (float*)d_ws;   // 128 * 6 floats = 3 KB scratch

    theta_kernel<<<1, BATCH, 0, stream>>>(rot, trans, scale, shear, theta);

    const int nblocks = BATCH * (IMH / TH) * (IMW / TW);   // 32768
    affine_sample_kernel<<<nblocks, 256, 0, stream>>>(img, theta, out);
}

// Round 6
// 51.872 us; speedup vs baseline: 2.4379x; 1.0694x over previous
//
#include <hip/hip_runtime.h>
#include <math.h>

// Problem constants (from reference): B=128, C=3, H=256, W=256, fp32.
#define BATCH 128
#define CHAN  3
#define IMH   256
#define IMW   256
#define NXCD  8
#define TW    16   // output tile width  (per block)
#define TH    16   // output tile height (per block)

// LDS staged tile: rows x stride. Stride 46 = even (ds_write_b64 alignment),
// holds up to 44 valid cols + the 2-float spill of the last guarded b64 write.
#define BH_T  42
#define BW_T  46

// ---------------------------------------------------------------------------
// Kernel 1: per-image linearized affine params -> prm[8*b..8*b+7]
//   ix(w,h) = Cx + a00*w + a01*h   (exact: reference map is affine in w,h)
//   hx/hy   = bbox half-widths of a 16x16 tile footprint (7.5*(|row|_1))
// ---------------------------------------------------------------------------
__global__ void param_kernel(const float* __restrict__ rot,
                             const float* __restrict__ trans,
                             const float* __restrict__ scale,
                             const float* __restrict__ shear,
                             float* __restrict__ prm) {
    int b = threadIdx.x;
    if (b >= BATCH) return;
    float r   = rot[b];
    float s   = scale[b];
    float c   = cosf(r);
    float sn  = sinf(r);
    float shx = shear[2 * b + 0];
    float shy = shear[2 * b + 1];
    float a00 = s * (c - sn * shy);
    float a01 = s * (c * shx - sn);
    float a10 = s * (sn + c * shy);
    float a11 = s * (sn * shx + c);
    float tx  = trans[2 * b + 0];
    float ty  = trans[2 * b + 1];
    // ix at (w=0,h=0) via the reference formula chain:
    float gx0 = 2.0f * 0.5f / (float)IMW - 1.0f;
    float gy0 = 2.0f * 0.5f / (float)IMH - 1.0f;
    float Cx  = ((a00 * gx0 + a01 * gy0 + tx + 1.0f) * (float)IMW - 1.0f) * 0.5f;
    float Cy  = ((a10 * gx0 + a11 * gy0 + ty + 1.0f) * (float)IMH - 1.0f) * 0.5f;
    float hx  = 7.5f * (fabsf(a00) + fabsf(a01));
    float hy  = 7.5f * (fabsf(a10) + fabsf(a11));
    float* o = prm + 8 * b;
    o[0] = a00; o[1] = a01; o[2] = Cx; o[3] = hx;
    o[4] = a10; o[5] = a11; o[6] = Cy; o[7] = hy;
}

// ---------------------------------------------------------------------------
// Kernel 2: affine grid + bilinear sample with LDS-staged input footprint.
// Block = 256 threads = one 16x16 output tile.
// Stager: 16 lanes x float2 wide x 16 rows tall per round; channel-inner;
// NO zero-fill -- addresses are clamped into the image, so staged garbage
// cells hold finite image values and every tap that could read them has
// weight exactly 0 (reference validity semantics). Typical cost: 2 rounds
// x (3 dwordx2 loads + 3 ds_write_b64).
// ---------------------------------------------------------------------------
__global__ __launch_bounds__(256) void affine_sample_kernel(
        const float* __restrict__ img,
        const float* __restrict__ prm,
        float* __restrict__ out) {
    __shared__ float tile[CHAN][BH_T][BW_T];   // 23,184 B -> 7 blocks/CU

    const int NBLK = BATCH * (IMH / TH) * (IMW / TW);   // 32768
    const int p = blockIdx.x;
    const int L = (p & (NXCD - 1)) * (NBLK / NXCD) + (p >> 3);  // XCD-chunked

    const int b  = L >> 8;            // 256 tiles per image
    const int tl = L & 255;
    const int w0 = (tl & 15) * TW;
    const int h0 = (tl >> 4) * TH;

    // per-image params: uniform index -> scalar loads
    const float* pr = prm + 8 * b;
    const float a00 = pr[0], a01 = pr[1], Cx = pr[2], hx = pr[3];
    const float a10 = pr[4], a11 = pr[5], Cy = pr[6], hy = pr[7];

    // --- block-uniform bbox of the input footprint (~15 VALU) --------------
    const float ixc = Cx + a00 * ((float)w0 + 7.5f) + a01 * ((float)h0 + 7.5f);
    const float iyc = Cy + a10 * ((float)w0 + 7.5f) + a11 * ((float)h0 + 7.5f);
    const int x_lo = min(max((int)floorf(ixc - hx), 0), IMW - 1);
    const int x_hi = min(max((int)floorf(ixc + hx) + 1, 0), IMW - 1);
    const int y_lo = min(max((int)floorf(iyc - hy), 0), IMH - 1);
    const int y_hi = min(max((int)floorf(iyc + hy) + 1, 0), IMH - 1);
    const int xs  = (x_lo - 1) & ~1;   // even staging origin (may be -2)
    const int ys  = y_lo - 1;          // staging origin      (may be -1)
    const int ncs = x_hi + 2 - xs;     // staged cols: x = xs .. x_hi+1
    const int nrs = y_hi + 2 - ys;     // staged rows: y = ys .. y_hi+1

    // --- per-thread sample coordinates (linearized, exact) -----------------
    const int t  = threadIdx.x;
    const int wq = w0 + (t & 15);
    const int hq = h0 + (t >> 4);
    const float ix = Cx + a00 * (float)wq + a01 * (float)hq;
    const float iy = Cy + a10 * (float)wq + a11 * (float)hq;

    const float x0f = floorf(ix);
    const float y0f = floorf(iy);
    const float wx1 = ix - x0f;
    const float wx0 = 1.0f - wx1;
    const float wy1 = iy - y0f;
    const float wy0 = 1.0f - wy1;

    const bool vx0 = (x0f >= 0.0f) & (x0f <= (float)(IMW - 1));
    const bool vx1 = (x0f >= -1.0f) & (x0f <= (float)(IMW - 2));   // x1 = x0+1
    const bool vy0 = (y0f >= 0.0f) & (y0f <= (float)(IMH - 1));
    const bool vy1 = (y0f >= -1.0f) & (y0f <= (float)(IMH - 2));   // y1 = y0+1

    const float w00 = (vx0 && vy0) ? (wx0 * wy0) : 0.0f;
    const float w10 = (vx1 && vy0) ? (wx1 * wy0) : 0.0f;
    const float w01 = (vx0 && vy1) ? (wx0 * wy1) : 0.0f;
    const float w11 = (vx1 && vy1) ? (wx1 * wy1) : 0.0f;

    const int x0i = (int)x0f;   // may be far out of range; weights cover it
    const int y0i = (int)y0f;

    const int plane = IMH * IMW;
    const int obase = (b * CHAN) * plane + hq * IMW + wq;
    const float* ibase = img + (size_t)(b * CHAN) * plane;

    // --- staged path iff footprint fits LDS. Block-uniform branch. ---------
    if (ncs <= 44 && nrs <= BH_T) {
        const int lx2 = (t & 15) << 1;            // 0,2,..,30
        const int lyr = t >> 4;                   // 0..15
        const int nsw = (ncs + 31) >> 5;          // 1 or 2 column sweeps
        const int nrd = (nrs + 15) >> 4;          // 1..3 row rounds
        for (int s = 0; s < nsw; ++s) {
            const int col = (s << 5) + lx2;
            int xg = xs + col;
            xg = min(max(xg, 0), IMW - 2);        // even-pair clamp (0,254 even)
            const bool wcol = col < ncs;
            for (int r = 0; r < nrd; ++r) {
                const int dy = (r << 4) + lyr;
                int yg = ys + dy;
                yg = min(max(yg, 0), IMH - 1);
                const float* src = ibase + yg * IMW + xg;
                const float2 v0 = *(const float2*)(src);
                const float2 v1 = *(const float2*)(src + plane);
                const float2 v2 = *(const float2*)(src + 2 * plane);
                if (wcol & (dy < nrs)) {
                    *(float2*)&tile[0][dy][col] = v0;
                    *(float2*)&tile[1][dy][col] = v1;
                    *(float2*)&tile[2][dy][col] = v2;
                }
            }
        }
        __syncthreads();

        // Gather from LDS. Clamp to the WRITTEN region so zero-weight taps
        // read staged (finite) cells, never uninitialized LDS.
        const int rx = min(max(x0i - xs, 0), ncs - 2);
        const int ry = min(max(y0i - ys, 0), nrs - 2);
#pragma unroll
        for (int c = 0; c < CHAN; ++c) {
            const float* tp = &tile[c][ry][rx];
            const float v = w00 * tp[0] + w10 * tp[1]
                          + w01 * tp[BW_T] + w11 * tp[BW_T + 1];
            out[obase + c * plane] = v;
        }
    } else {
        // fallback: direct global gathers (unreachable for this input dist;
        // kept for safety at extreme shear/scale)
        const int x0c = min(max(x0i, 0), IMW - 1);
        const int x1c = min(max(x0i + 1, 0), IMW - 1);
        const int y0c = min(max(y0i, 0), IMH - 1);
        const int y1c = min(max(y0i + 1, 0), IMH - 1);
        const int i00 = y0c * IMW + x0c;
        const int i10 = y0c * IMW + x1c;
        const int i01 = y1c * IMW + x0c;
        const int i11 = y1c * IMW + x1c;
#pragma unroll
        for (int c = 0; c < CHAN; ++c) {
            const float* p2 = ibase + c * plane;
            const float v = w00 * p2[i00] + w10 * p2[i10]
                          + w01 * p2[i01] + w11 * p2[i11];
            out[obase + c * plane] = v;
        }
    }
}

extern "C" void kernel_launch(void* const* d_in, const int* in_sizes, int n_in,
                              void* d_out, int out_size, void* d_ws, size_t ws_size,
                              hipStream_t stream) {
    const float* img   = (const float*)d_in[0];
    const float* rot   = (const float*)d_in[1];
    const float* trans = (const float*)d_in[2];
    const float* scale = (const float*)d_in[3];
    const float* shear = (const float*)d_in[4];
    float* out = (float*)d_out;
    float* prm = (float*)d_ws;   // 128 * 8 floats = 4 KB scratch

    param_kernel<<<1, BATCH, 0, stream>>>(rot, trans, scale, shear, prm);

    const int nblocks = BATCH * (IMH / TH) * (IMW / TW);   // 32768
    affine_sample_kernel<<<nblocks, 256, 0, stream>>>(img, prm, out);
}

// Round 7
// 50.023 us; speedup vs baseline: 2.5280x; 1.0370x over previous
//
#include <hip/hip_runtime.h>
#include <math.h>

// Problem constants (from reference): B=128, C=3, H=256, W=256, fp32.
#define BATCH 128
#define CHAN  3
#define IMH   256
#define IMW   256
#define NXCD  8
#define TW    16   // output tile width  (per block)
#define TH    16   // output tile height (per block)

// LDS staged tile: rows x stride. Stride 45 (odd): no b64 alignment needed
// (pair writes emitted as ds_write2_b32), 3*42*45*4 = 22,680 B -> 7 blocks/CU.
#define BH_T  42
#define BW_T  45
#define NC_MAX 44   // max staged cols (pair-write may touch col NC_MAX-1+1 = 44)

// ---------------------------------------------------------------------------
// Single fused kernel: per-image affine params are recomputed by every block
// (uniform scalar math incl. sincos -- ~40 ops, fills latency slack and kills
// the separate param dispatch + its prm-load round trip).
// Block = 256 threads = one 16x16 output tile, LDS-staged input footprint.
// ---------------------------------------------------------------------------
__global__ __launch_bounds__(256) void affine_sample_kernel(
        const float* __restrict__ img,
        const float* __restrict__ rot,
        const float* __restrict__ trans,
        const float* __restrict__ scale,
        const float* __restrict__ shear,
        float* __restrict__ out) {
    __shared__ float tile[CHAN][BH_T][BW_T];   // 22,680 B

    const int NBLK = BATCH * (IMH / TH) * (IMW / TW);   // 32768
    const int p = blockIdx.x;
    const int L = (p & (NXCD - 1)) * (NBLK / NXCD) + (p >> 3);  // XCD-chunked

    const int b  = L >> 8;            // 256 tiles per image
    const int tl = L & 255;
    const int w0 = (tl & 15) * TW;
    const int h0 = (tl >> 4) * TH;

    // --- per-image params, block-uniform (reference math) ------------------
    const float r   = rot[b];
    const float s   = scale[b];
    const float shx = shear[2 * b + 0];
    const float shy = shear[2 * b + 1];
    const float txr = trans[2 * b + 0];
    const float tyr = trans[2 * b + 1];
    const float c  = cosf(r);
    const float sn = sinf(r);
    const float a00 = s * (c - sn * shy);
    const float a01 = s * (c * shx - sn);
    const float a10 = s * (sn + c * shy);
    const float a11 = s * (sn * shx + c);
    // linearized: ix(w,h) = Cx + a00*w + a01*h (exact; map is affine in w,h)
    const float g0x = 1.0f / (float)IMW - 1.0f;   // gx at w=0
    const float g0y = 1.0f / (float)IMH - 1.0f;   // gy at h=0
    const float Cx = ((a00 * g0x + a01 * g0y + txr + 1.0f) * (float)IMW - 1.0f) * 0.5f;
    const float Cy = ((a10 * g0x + a11 * g0y + tyr + 1.0f) * (float)IMH - 1.0f) * 0.5f;
    const float hx = 7.5f * (fabsf(a00) + fabsf(a01));
    const float hy = 7.5f * (fabsf(a10) + fabsf(a11));

    // --- block-uniform bbox of the input footprint -------------------------
    const float ixc = Cx + a00 * ((float)w0 + 7.5f) + a01 * ((float)h0 + 7.5f);
    const float iyc = Cy + a10 * ((float)w0 + 7.5f) + a11 * ((float)h0 + 7.5f);
    const int xlu = (int)floorf(ixc - hx);        // unclamped
    const int xhu = (int)floorf(ixc + hx) + 1;
    const int ylu = (int)floorf(iyc - hy);
    const int yhu = (int)floorf(iyc + hy) + 1;
    // all 4 taps of every pixel provably in-range (1 px FP-jitter margin)
    const bool interior = (xlu >= 1) & (xhu <= IMW - 2) & (ylu >= 1) & (yhu <= IMH - 2);

    const int x_lo = min(max(xlu, 0), IMW - 1);
    const int x_hi = min(max(xhu, 0), IMW - 1);
    const int y_lo = min(max(ylu, 0), IMH - 1);
    const int y_hi = min(max(yhu, 0), IMH - 1);
    const int xs  = (x_lo - 1) & ~1;   // even staging origin (may be -2)
    const int ys  = y_lo - 1;          // staging origin      (may be -1)
    const int ncs = x_hi + 2 - xs;     // staged cols: x = xs .. x_hi+1
    const int nrs = y_hi + 2 - ys;     // staged rows: y = ys .. y_hi+1

    // --- per-thread sample coordinates (linearized, exact) -----------------
    const int t  = threadIdx.x;
    const int wq = w0 + (t & 15);
    const int hq = h0 + (t >> 4);
    const float ix = Cx + a00 * (float)wq + a01 * (float)hq;
    const float iy = Cy + a10 * (float)wq + a11 * (float)hq;

    const float x0f = floorf(ix);
    const float y0f = floorf(iy);
    const float wx1 = ix - x0f;
    const float wx0 = 1.0f - wx1;
    const float wy1 = iy - y0f;
    const float wy0 = 1.0f - wy1;

    float w00, w10, w01, w11;
    if (interior) {                     // block-uniform branch, no divergence
        w00 = wx0 * wy0;
        w10 = wx1 * wy0;
        w01 = wx0 * wy1;
        w11 = wx1 * wy1;
    } else {
        const bool vx0 = (x0f >= 0.0f) & (x0f <= (float)(IMW - 1));
        const bool vx1 = (x0f >= -1.0f) & (x0f <= (float)(IMW - 2));
        const bool vy0 = (y0f >= 0.0f) & (y0f <= (float)(IMH - 1));
        const bool vy1 = (y0f >= -1.0f) & (y0f <= (float)(IMH - 2));
        w00 = (vx0 && vy0) ? (wx0 * wy0) : 0.0f;
        w10 = (vx1 && vy0) ? (wx1 * wy0) : 0.0f;
        w01 = (vx0 && vy1) ? (wx0 * wy1) : 0.0f;
        w11 = (vx1 && vy1) ? (wx1 * wy1) : 0.0f;
    }

    const int x0i = (int)x0f;   // may be far out of range; weights cover it
    const int y0i = (int)y0f;

    const int plane = IMH * IMW;
    const int obase = (b * CHAN) * plane + hq * IMW + wq;
    const float* ibase = img + (size_t)(b * CHAN) * plane;

    // --- staged path iff footprint fits LDS. Block-uniform branch. ---------
    if (ncs <= NC_MAX && nrs <= BH_T) {
        // Stager: 16 lanes x float2 wide x 16 rows per round, channel-inner.
        // No zero-fill: addresses clamped into the image; any tap that could
        // read a garbage cell has weight exactly 0 (reference semantics).
        const int lx2 = (t & 15) << 1;            // 0,2,..,30
        const int lyr = t >> 4;                   // 0..15
        const int nsw = (ncs + 31) >> 5;          // 1 or 2 column sweeps
        const int nrd = (nrs + 15) >> 4;          // 1..3 row rounds
        for (int sw = 0; sw < nsw; ++sw) {
            const int col = (sw << 5) + lx2;
            int xg = xs + col;
            xg = min(max(xg, 0), IMW - 2);        // even-pair clamp
            const bool wcol = col < ncs;
            for (int rr = 0; rr < nrd; ++rr) {
                const int dy = (rr << 4) + lyr;
                int yg = ys + dy;
                yg = min(max(yg, 0), IMH - 1);
                const float* src = ibase + yg * IMW + xg;
                const float2 v0 = *(const float2*)(src);
                const float2 v1 = *(const float2*)(src + plane);
                const float2 v2 = *(const float2*)(src + 2 * plane);
                if (wcol & (dy < nrs)) {
                    tile[0][dy][col]     = v0.x;   // adjacent pair ->
                    tile[0][dy][col + 1] = v0.y;   //   ds_write2_b32
                    tile[1][dy][col]     = v1.x;
                    tile[1][dy][col + 1] = v1.y;
                    tile[2][dy][col]     = v2.x;
                    tile[2][dy][col + 1] = v2.y;
                }
            }
        }
        __syncthreads();

        // Gather from LDS. Clamp to the WRITTEN region so zero-weight taps
        // read staged (finite) cells, never uninitialized LDS.
        const int rx = min(max(x0i - xs, 0), ncs - 2);
        const int ry = min(max(y0i - ys, 0), nrs - 2);
#pragma unroll
        for (int cc = 0; cc < CHAN; ++cc) {
            const float* tp = &tile[cc][ry][rx];
            const float v = w00 * tp[0] + w10 * tp[1]
                          + w01 * tp[BW_T] + w11 * tp[BW_T + 1];
            out[obase + cc * plane] = v;
        }
    } else {
        // fallback: direct global gathers (extreme shear/scale only)
        const int x0c = min(max(x0i, 0), IMW - 1);
        const int x1c = min(max(x0i + 1, 0), IMW - 1);
        const int y0c = min(max(y0i, 0), IMH - 1);
        const int y1c = min(max(y0i + 1, 0), IMH - 1);
        const int i00 = y0c * IMW + x0c;
        const int i10 = y0c * IMW + x1c;
        const int i01 = y1c * IMW + x0c;
        const int i11 = y1c * IMW + x1c;
#pragma unroll
        for (int cc = 0; cc < CHAN; ++cc) {
            const float* p2 = ibase + cc * plane;
            const float v = w00 * p2[i00] + w10 * p2[i10]
                          + w01 * p2[i01] + w11 * p2[i11];
            out[obase + cc * plane] = v;
        }
    }
}

extern "C" void kernel_launch(void* const* d_in, const int* in_sizes, int n_in,
                              void* d_out, int out_size, void* d_ws, size_t ws_size,
                              hipStream_t stream) {
    const float* img   = (const float*)d_in[0];
    const float* rot   = (const float*)d_in[1];
    const float* trans = (const float*)d_in[2];
    const float* scale = (const float*)d_in[3];
    const float* shear = (const float*)d_in[4];
    float* out = (float*)d_out;

    const int nblocks = BATCH * (IMH / TH) * (IMW / TW);   // 32768
    affine_sample_kernel<<<nblocks, 256, 0, stream>>>(img, rot, trans, scale,
                                                      shear, out);
}

// Round 8
// 43.595 us; speedup vs baseline: 2.9008x; 1.1475x over previous
//
#include <hip/hip_runtime.h>
#include <math.h>

// Problem constants (from reference): B=128, C=3, H=256, W=256, fp32.
#define BATCH 128
#define CHAN  3
#define IMH   256
#define IMW   256
#define NXCD  8
#define TW    32   // output tile width  (per block) -- 2 px per thread in w
#define TH    16   // output tile height (per block)

// LDS staged tile: rows x stride. 3*42*45*4 = 22,680 B -> 7 blocks/CU.
#define BH_T   42
#define BW_T   45
#define NC_MAX 44   // max staged cols (even col < ncs, pair touches <= 43)

// ---------------------------------------------------------------------------
// Single fused kernel. Block = 256 threads = one 32x16 output tile, 2 px per
// thread (adjacent in w -> float2 stores). Input footprint staged in LDS.
// Per-image affine params recomputed per block (uniform math, amortized over
// 512 px). Stager lane map: 32 float2-lanes (64 cols) x 8 rows per round --
// covers any staged width in one sweep; loads are guarded so idle lanes
// issue no memory requests.
// ---------------------------------------------------------------------------
__global__ __launch_bounds__(256) void affine_sample_kernel(
        const float* __restrict__ img,
        const float* __restrict__ rot,
        const float* __restrict__ trans,
        const float* __restrict__ scale,
        const float* __restrict__ shear,
        float* __restrict__ out) {
    __shared__ float tile[CHAN][BH_T][BW_T];   // 22,680 B

    const int NBLK = BATCH * (IMH / TH) * (IMW / TW);   // 128*16*8 = 16384
    const int p = blockIdx.x;
    const int L = (p & (NXCD - 1)) * (NBLK / NXCD) + (p >> 3);  // XCD-chunked

    const int b  = L >> 7;            // 128 tiles per image
    const int tl = L & 127;
    const int w0 = (tl & 7) * TW;
    const int h0 = (tl >> 3) * TH;

    // --- per-image params, block-uniform (reference math) ------------------
    const float r   = rot[b];
    const float s   = scale[b];
    const float shx = shear[2 * b + 0];
    const float shy = shear[2 * b + 1];
    const float txr = trans[2 * b + 0];
    const float tyr = trans[2 * b + 1];
    const float c  = cosf(r);
    const float sn = sinf(r);
    const float a00 = s * (c - sn * shy);
    const float a01 = s * (c * shx - sn);
    const float a10 = s * (sn + c * shy);
    const float a11 = s * (sn * shx + c);
    // linearized: ix(w,h) = Cx + a00*w + a01*h (exact; map is affine in w,h)
    const float g0x = 1.0f / (float)IMW - 1.0f;   // gx at w=0
    const float g0y = 1.0f / (float)IMH - 1.0f;   // gy at h=0
    const float Cx = ((a00 * g0x + a01 * g0y + txr + 1.0f) * (float)IMW - 1.0f) * 0.5f;
    const float Cy = ((a10 * g0x + a11 * g0y + tyr + 1.0f) * (float)IMH - 1.0f) * 0.5f;
    const float hx = 15.5f * fabsf(a00) + 7.5f * fabsf(a01);
    const float hy = 15.5f * fabsf(a10) + 7.5f * fabsf(a11);

    // --- block-uniform bbox of the input footprint -------------------------
    const float ixc = Cx + a00 * ((float)w0 + 15.5f) + a01 * ((float)h0 + 7.5f);
    const float iyc = Cy + a10 * ((float)w0 + 15.5f) + a11 * ((float)h0 + 7.5f);
    const int xlu = (int)floorf(ixc - hx);        // unclamped
    const int xhu = (int)floorf(ixc + hx) + 1;
    const int ylu = (int)floorf(iyc - hy);
    const int yhu = (int)floorf(iyc + hy) + 1;
    // all 4 taps of every pixel provably in-range
    const bool interior = (xlu >= 1) & (xhu <= IMW - 2) & (ylu >= 1) & (yhu <= IMH - 2);

    const int x_lo = min(max(xlu, 0), IMW - 1);
    const int x_hi = min(max(xhu, 0), IMW - 1);
    const int y_lo = min(max(ylu, 0), IMH - 1);
    const int y_hi = min(max(yhu, 0), IMH - 1);
    const int xs  = (x_lo - 1) & ~1;   // even staging origin (may be -2)
    const int ys  = y_lo - 1;          // staging origin      (may be -1)
    const int ncs = x_hi + 2 - xs;     // staged cols: x = xs .. x_hi+1
    const int nrs = y_hi + 2 - ys;     // staged rows: y = ys .. y_hi+1

    // --- per-thread sample coordinates: 2 adjacent px ----------------------
    const int t  = threadIdx.x;
    const int wq = w0 + ((t & 15) << 1);          // even
    const int hq = h0 + (t >> 4);
    const float ixa = Cx + a00 * (float)wq + a01 * (float)hq;
    const float iya = Cy + a10 * (float)wq + a11 * (float)hq;
    const float ixb = ixa + a00;
    const float iyb = iya + a10;

    const float x0fa = floorf(ixa), y0fa = floorf(iya);
    const float x0fb = floorf(ixb), y0fb = floorf(iyb);
    const float wx1a = ixa - x0fa, wy1a = iya - y0fa;
    const float wx1b = ixb - x0fb, wy1b = iyb - y0fb;
    const float wx0a = 1.0f - wx1a, wy0a = 1.0f - wy1a;
    const float wx0b = 1.0f - wx1b, wy0b = 1.0f - wy1b;

    float w00a, w10a, w01a, w11a, w00b, w10b, w01b, w11b;
    if (interior) {                     // block-uniform branch
        w00a = wx0a * wy0a; w10a = wx1a * wy0a;
        w01a = wx0a * wy1a; w11a = wx1a * wy1a;
        w00b = wx0b * wy0b; w10b = wx1b * wy0b;
        w01b = wx0b * wy1b; w11b = wx1b * wy1b;
    } else {
        const bool vx0a = (x0fa >= 0.0f) & (x0fa <= (float)(IMW - 1));
        const bool vx1a = (x0fa >= -1.0f) & (x0fa <= (float)(IMW - 2));
        const bool vy0a = (y0fa >= 0.0f) & (y0fa <= (float)(IMH - 1));
        const bool vy1a = (y0fa >= -1.0f) & (y0fa <= (float)(IMH - 2));
        w00a = (vx0a && vy0a) ? (wx0a * wy0a) : 0.0f;
        w10a = (vx1a && vy0a) ? (wx1a * wy0a) : 0.0f;
        w01a = (vx0a && vy1a) ? (wx0a * wy1a) : 0.0f;
        w11a = (vx1a && vy1a) ? (wx1a * wy1a) : 0.0f;
        const bool vx0b = (x0fb >= 0.0f) & (x0fb <= (float)(IMW - 1));
        const bool vx1b = (x0fb >= -1.0f) & (x0fb <= (float)(IMW - 2));
        const bool vy0b = (y0fb >= 0.0f) & (y0fb <= (float)(IMH - 1));
        const bool vy1b = (y0fb >= -1.0f) & (y0fb <= (float)(IMH - 2));
        w00b = (vx0b && vy0b) ? (wx0b * wy0b) : 0.0f;
        w10b = (vx1b && vy0b) ? (wx1b * wy0b) : 0.0f;
        w01b = (vx0b && vy1b) ? (wx0b * wy1b) : 0.0f;
        w11b = (vx1b && vy1b) ? (wx1b * wy1b) : 0.0f;
    }

    const int x0ia = (int)x0fa, y0ia = (int)y0fa;
    const int x0ib = (int)x0fb, y0ib = (int)y0fb;

    const int plane = IMH * IMW;
    const int obase = (b * CHAN) * plane + hq * IMW + wq;
    const float* ibase = img + (size_t)(b * CHAN) * plane;

    // --- staged path iff footprint fits LDS. Block-uniform branch. ---------
    if (ncs <= NC_MAX && nrs <= BH_T) {
        // Stager: 32 float2-lanes (64 cols) x 8 rows per round; channel-inner.
        // No zero-fill: addresses clamped into the image; any tap that could
        // read a garbage cell has weight exactly 0 (reference semantics).
        const int lx2 = (t & 31) << 1;            // 0,2,..,62
        const int lyr = t >> 5;                   // 0..7
        const int nrd = (nrs + 7) >> 3;           // 1..6 row rounds
        const bool wcol = lx2 < ncs;
        const int xg = min(max(xs + lx2, 0), IMW - 2);   // even
        for (int rr = 0; rr < nrd; ++rr) {
            const int dy = (rr << 3) + lyr;
            if (wcol & (dy < nrs)) {
                const int yg = min(max(ys + dy, 0), IMH - 1);
                const float* src = ibase + yg * IMW + xg;
                const float2 v0 = *(const float2*)(src);
                const float2 v1 = *(const float2*)(src + plane);
                const float2 v2 = *(const float2*)(src + 2 * plane);
                tile[0][dy][lx2]     = v0.x;
                tile[0][dy][lx2 + 1] = v0.y;
                tile[1][dy][lx2]     = v1.x;
                tile[1][dy][lx2 + 1] = v1.y;
                tile[2][dy][lx2]     = v2.x;
                tile[2][dy][lx2 + 1] = v2.y;
            }
        }
        __syncthreads();

        // Gather from LDS. Interior: unclamped (halo + bbox proof covers it).
        // Border blocks: clamp into the written region so zero-weight taps
        // read staged (finite) cells, never uninitialized LDS.
        int rxa, rya, rxb, ryb;
        if (interior) {
            rxa = x0ia - xs;  rya = y0ia - ys;
            rxb = x0ib - xs;  ryb = y0ib - ys;
        } else {
            rxa = min(max(x0ia - xs, 0), ncs - 2);
            rya = min(max(y0ia - ys, 0), nrs - 2);
            rxb = min(max(x0ib - xs, 0), ncs - 2);
            ryb = min(max(y0ib - ys, 0), nrs - 2);
        }
#pragma unroll
        for (int cc = 0; cc < CHAN; ++cc) {
            const float* tpa = &tile[cc][rya][rxa];
            const float* tpb = &tile[cc][ryb][rxb];
            float2 v;
            v.x = w00a * tpa[0] + w10a * tpa[1]
                + w01a * tpa[BW_T] + w11a * tpa[BW_T + 1];
            v.y = w00b * tpb[0] + w10b * tpb[1]
                + w01b * tpb[BW_T] + w11b * tpb[BW_T + 1];
            *(float2*)&out[obase + cc * plane] = v;
        }
    } else {
        // fallback: direct global gathers (extreme shear/rotation tail only)
        const int x0ca = min(max(x0ia, 0), IMW - 1);
        const int x1ca = min(max(x0ia + 1, 0), IMW - 1);
        const int y0ca = min(max(y0ia, 0), IMH - 1);
        const int y1ca = min(max(y0ia + 1, 0), IMH - 1);
        const int x0cb = min(max(x0ib, 0), IMW - 1);
        const int x1cb = min(max(x0ib + 1, 0), IMW - 1);
        const int y0cb = min(max(y0ib, 0), IMH - 1);
        const int y1cb = min(max(y0ib + 1, 0), IMH - 1);
#pragma unroll
        for (int cc = 0; cc < CHAN; ++cc) {
            const float* p2 = ibase + cc * plane;
            float2 v;
            v.x = w00a * p2[y0ca * IMW + x0ca] + w10a * p2[y0ca * IMW + x1ca]
                + w01a * p2[y1ca * IMW + x0ca] + w11a * p2[y1ca * IMW + x1ca];
            v.y = w00b * p2[y0cb * IMW + x0cb] + w10b * p2[y0cb * IMW + x1cb]
                + w01b * p2[y1cb * IMW + x0cb] + w11b * p2[y1cb * IMW + x1cb];
            *(float2*)&out[obase + cc * plane] = v;
        }
    }
}

extern "C" void kernel_launch(void* const* d_in, const int* in_sizes, int n_in,
                              void* d_out, int out_size, void* d_ws, size_t ws_size,
                              hipStream_t stream) {
    const float* img   = (const float*)d_in[0];
    const float* rot   = (const float*)d_in[1];
    const float* trans = (const float*)d_in[2];
    const float* scale = (const float*)d_in[3];
    const float* shear = (const float*)d_in[4];
    float* out = (float*)d_out;

    const int nblocks = BATCH * (IMH / TH) * (IMW / TW);   // 16384
    affine_sample_kernel<<<nblocks, 256, 0, stream>>>(img, rot, trans, scale,
                                                      shear, out);
}

// Round 9
// 43.413 us; speedup vs baseline: 2.9129x; 1.0042x over previous
//
#include <hip/hip_runtime.h>
#include <math.h>

// Problem constants (from reference): B=128, C=3, H=256, W=256, fp32.
#define BATCH 128
#define CHAN  3
#define IMH   256
#define IMW   256
#define NXCD  8
#define TW    32   // output tile width  (per block)
#define TH    16   // output tile height (per block) -- 2 px per thread in h

// LDS staged tile: rows x stride. 3*42*45*4 = 22,680 B -> 7 blocks/CU.
#define BH_T   42
#define BW_T   45
#define NC_MAX 44   // max staged cols (even col < ncs, pair touches <= 43)

// ---------------------------------------------------------------------------
// Single fused kernel. Block = 256 threads = one 32x16 output tile, 2 px per
// thread STACKED IN H (wave = 32 w-lanes x 2 h-groups): LDS gather lanes have
// rx stride 1 -> addresses spread across all 32 banks (<=2-way, free), unlike
// the stride-2 (2px-in-w) map which stacked 4-way conflicts on even banks.
// Input footprint staged in LDS; per-image affine params recomputed per block.
// ---------------------------------------------------------------------------
__global__ __launch_bounds__(256) void affine_sample_kernel(
        const float* __restrict__ img,
        const float* __restrict__ rot,
        const float* __restrict__ trans,
        const float* __restrict__ scale,
        const float* __restrict__ shear,
        float* __restrict__ out) {
    __shared__ float tile[CHAN][BH_T][BW_T];   // 22,680 B

    const int NBLK = BATCH * (IMH / TH) * (IMW / TW);   // 128*16*8 = 16384
    const int p = blockIdx.x;
    const int L = (p & (NXCD - 1)) * (NBLK / NXCD) + (p >> 3);  // XCD-chunked

    const int b  = L >> 7;            // 128 tiles per image
    const int tl = L & 127;
    const int w0 = (tl & 7) * TW;
    const int h0 = (tl >> 3) * TH;

    // --- per-image params, block-uniform (reference math) ------------------
    const float r   = rot[b];
    const float s   = scale[b];
    const float shx = shear[2 * b + 0];
    const float shy = shear[2 * b + 1];
    const float txr = trans[2 * b + 0];
    const float tyr = trans[2 * b + 1];
    const float c  = cosf(r);
    const float sn = sinf(r);
    const float a00 = s * (c - sn * shy);
    const float a01 = s * (c * shx - sn);
    const float a10 = s * (sn + c * shy);
    const float a11 = s * (sn * shx + c);
    // linearized: ix(w,h) = Cx + a00*w + a01*h (exact; map is affine in w,h)
    const float g0x = 1.0f / (float)IMW - 1.0f;   // gx at w=0
    const float g0y = 1.0f / (float)IMH - 1.0f;   // gy at h=0
    const float Cx = ((a00 * g0x + a01 * g0y + txr + 1.0f) * (float)IMW - 1.0f) * 0.5f;
    const float Cy = ((a10 * g0x + a11 * g0y + tyr + 1.0f) * (float)IMH - 1.0f) * 0.5f;
    const float hx = 15.5f * fabsf(a00) + 7.5f * fabsf(a01);
    const float hy = 15.5f * fabsf(a10) + 7.5f * fabsf(a11);

    // --- block-uniform bbox of the input footprint -------------------------
    const float ixc = Cx + a00 * ((float)w0 + 15.5f) + a01 * ((float)h0 + 7.5f);
    const float iyc = Cy + a10 * ((float)w0 + 15.5f) + a11 * ((float)h0 + 7.5f);
    const int xlu = (int)floorf(ixc - hx);        // unclamped
    const int xhu = (int)floorf(ixc + hx) + 1;
    const int ylu = (int)floorf(iyc - hy);
    const int yhu = (int)floorf(iyc + hy) + 1;
    // all 4 taps of every pixel provably in-range
    const bool interior = (xlu >= 1) & (xhu <= IMW - 2) & (ylu >= 1) & (yhu <= IMH - 2);

    const int x_lo = min(max(xlu, 0), IMW - 1);
    const int x_hi = min(max(xhu, 0), IMW - 1);
    const int y_lo = min(max(ylu, 0), IMH - 1);
    const int y_hi = min(max(yhu, 0), IMH - 1);
    const int xs  = (x_lo - 1) & ~1;   // even staging origin (may be -2)
    const int ys  = y_lo - 1;          // staging origin      (may be -1)
    const int ncs = x_hi + 2 - xs;     // staged cols: x = xs .. x_hi+1
    const int nrs = y_hi + 2 - ys;     // staged rows: y = ys .. y_hi+1

    // --- per-thread sample coordinates: 2 px stacked in h ------------------
    const int t  = threadIdx.x;
    const int wq = w0 + (t & 31);
    const int hq = h0 + ((t >> 5) << 1);          // even row; px at hq, hq+1
    const float ixa = Cx + a00 * (float)wq + a01 * (float)hq;
    const float iya = Cy + a10 * (float)wq + a11 * (float)hq;
    const float ixb = ixa + a01;
    const float iyb = iya + a11;

    const float x0fa = floorf(ixa), y0fa = floorf(iya);
    const float x0fb = floorf(ixb), y0fb = floorf(iyb);
    const float wx1a = ixa - x0fa, wy1a = iya - y0fa;
    const float wx1b = ixb - x0fb, wy1b = iyb - y0fb;
    const float wx0a = 1.0f - wx1a, wy0a = 1.0f - wy1a;
    const float wx0b = 1.0f - wx1b, wy0b = 1.0f - wy1b;

    float w00a, w10a, w01a, w11a, w00b, w10b, w01b, w11b;
    if (interior) {                     // block-uniform branch
        w00a = wx0a * wy0a; w10a = wx1a * wy0a;
        w01a = wx0a * wy1a; w11a = wx1a * wy1a;
        w00b = wx0b * wy0b; w10b = wx1b * wy0b;
        w01b = wx0b * wy1b; w11b = wx1b * wy1b;
    } else {
        const bool vx0a = (x0fa >= 0.0f) & (x0fa <= (float)(IMW - 1));
        const bool vx1a = (x0fa >= -1.0f) & (x0fa <= (float)(IMW - 2));
        const bool vy0a = (y0fa >= 0.0f) & (y0fa <= (float)(IMH - 1));
        const bool vy1a = (y0fa >= -1.0f) & (y0fa <= (float)(IMH - 2));
        w00a = (vx0a && vy0a) ? (wx0a * wy0a) : 0.0f;
        w10a = (vx1a && vy0a) ? (wx1a * wy0a) : 0.0f;
        w01a = (vx0a && vy1a) ? (wx0a * wy1a) : 0.0f;
        w11a = (vx1a && vy1a) ? (wx1a * wy1a) : 0.0f;
        const bool vx0b = (x0fb >= 0.0f) & (x0fb <= (float)(IMW - 1));
        const bool vx1b = (x0fb >= -1.0f) & (x0fb <= (float)(IMW - 2));
        const bool vy0b = (y0fb >= 0.0f) & (y0fb <= (float)(IMH - 1));
        const bool vy1b = (y0fb >= -1.0f) & (y0fb <= (float)(IMH - 2));
        w00b = (vx0b && vy0b) ? (wx0b * wy0b) : 0.0f;
        w10b = (vx1b && vy0b) ? (wx1b * wy0b) : 0.0f;
        w01b = (vx0b && vy1b) ? (wx0b * wy1b) : 0.0f;
        w11b = (vx1b && vy1b) ? (wx1b * wy1b) : 0.0f;
    }

    const int x0ia = (int)x0fa, y0ia = (int)y0fa;
    const int x0ib = (int)x0fb, y0ib = (int)y0fb;

    const int plane = IMH * IMW;
    const int obase = (b * CHAN) * plane + hq * IMW + wq;
    const float* ibase = img + (size_t)(b * CHAN) * plane;

    // --- staged path iff footprint fits LDS. Block-uniform branch. ---------
    if (ncs <= NC_MAX && nrs <= BH_T) {
        // Stager: 32 float2-lanes (64 cols) x 8 rows per round; channel-inner.
        // No zero-fill: addresses clamped into the image; any tap that could
        // read a garbage cell has weight exactly 0 (reference semantics).
        const int lx2 = (t & 31) << 1;            // 0,2,..,62
        const int lyr = t >> 5;                   // 0..7
        const int nrd = (nrs + 7) >> 3;           // 1..6 row rounds
        const bool wcol = lx2 < ncs;
        const int xg = min(max(xs + lx2, 0), IMW - 2);   // even
        for (int rr = 0; rr < nrd; ++rr) {
            const int dy = (rr << 3) + lyr;
            if (wcol & (dy < nrs)) {
                const int yg = min(max(ys + dy, 0), IMH - 1);
                const float* src = ibase + yg * IMW + xg;
                const float2 v0 = *(const float2*)(src);
                const float2 v1 = *(const float2*)(src + plane);
                const float2 v2 = *(const float2*)(src + 2 * plane);
                tile[0][dy][lx2]     = v0.x;
                tile[0][dy][lx2 + 1] = v0.y;
                tile[1][dy][lx2]     = v1.x;
                tile[1][dy][lx2 + 1] = v1.y;
                tile[2][dy][lx2]     = v2.x;
                tile[2][dy][lx2 + 1] = v2.y;
            }
        }
        __syncthreads();

        // Gather from LDS. Interior: unclamped (halo + bbox proof covers it).
        // Border blocks: clamp into the written region so zero-weight taps
        // read staged (finite) cells, never uninitialized LDS.
        int rxa, rya, rxb, ryb;
        if (interior) {
            rxa = x0ia - xs;  rya = y0ia - ys;
            rxb = x0ib - xs;  ryb = y0ib - ys;
        } else {
            rxa = min(max(x0ia - xs, 0), ncs - 2);
            rya = min(max(y0ia - ys, 0), nrs - 2);
            rxb = min(max(x0ib - xs, 0), ncs - 2);
            ryb = min(max(y0ib - ys, 0), nrs - 2);
        }
#pragma unroll
        for (int cc = 0; cc < CHAN; ++cc) {
            const float* tpa = &tile[cc][rya][rxa];
            const float* tpb = &tile[cc][ryb][rxb];
            const float va = w00a * tpa[0] + w10a * tpa[1]
                           + w01a * tpa[BW_T] + w11a * tpa[BW_T + 1];
            const float vb = w00b * tpb[0] + w10b * tpb[1]
                           + w01b * tpb[BW_T] + w11b * tpb[BW_T + 1];
            out[obase + cc * plane]       = va;
            out[obase + cc * plane + IMW] = vb;
        }
    } else {
        // fallback: direct global gathers (extreme shear/rotation tail only)
        const int x0ca = min(max(x0ia, 0), IMW - 1);
        const int x1ca = min(max(x0ia + 1, 0), IMW - 1);
        const int y0ca = min(max(y0ia, 0), IMH - 1);
        const int y1ca = min(max(y0ia + 1, 0), IMH - 1);
        const int x0cb = min(max(x0ib, 0), IMW - 1);
        const int x1cb = min(max(x0ib + 1, 0), IMW - 1);
        const int y0cb = min(max(y0ib, 0), IMH - 1);
        const int y1cb = min(max(y0ib + 1, 0), IMH - 1);
#pragma unroll
        for (int cc = 0; cc < CHAN; ++cc) {
            const float* p2 = ibase + cc * plane;
            const float va = w00a * p2[y0ca * IMW + x0ca] + w10a * p2[y0ca * IMW + x1ca]
                           + w01a * p2[y1ca * IMW + x0ca] + w11a * p2[y1ca * IMW + x1ca];
            const float vb = w00b * p2[y0cb * IMW + x0cb] + w10b * p2[y0cb * IMW + x1cb]
                           + w01b * p2[y1cb * IMW + x0cb] + w11b * p2[y1cb * IMW + x1cb];
            out[obase + cc * plane]       = va;
            out[obase + cc * plane + IMW] = vb;
        }
    }
}

extern "C" void kernel_launch(void* const* d_in, const int* in_sizes, int n_in,
                              void* d_out, int out_size, void* d_ws, size_t ws_size,
                              hipStream_t stream) {
    const float* img   = (const float*)d_in[0];
    const float* rot   = (const float*)d_in[1];
    const float* trans = (const float*)d_in[2];
    const float* scale = (const float*)d_in[3];
    const float* shear = (const float*)d_in[4];
    float* out = (float*)d_out;

    const int nblocks = BATCH * (IMH / TH) * (IMW / TW);   // 16384
    affine_sample_kernel<<<nblocks, 256, 0, stream>>>(img, rot, trans, scale,
                                                      shear, out);
}

// Round 10
// 41.718 us; speedup vs baseline: 3.0313x; 1.0406x over previous
//
#include <hip/hip_runtime.h>
#include <math.h>

// Problem constants (from reference): B=128, C=3, H=256, W=256, fp32.
#define BATCH 128
#define CHAN  3
#define IMH   256
#define IMW   256
#define NXCD  8
#define TW    32   // output tile width  (per block)
#define TH    16   // output tile height (per block) -- 2 px per thread in h

// LDS staged tile: rows x stride. 3*42*45*4 = 22,680 B -> 7 blocks/CU.
#define BH_T   42
#define BW_T   45
#define NC_MAX 44   // max staged cols (even col < ncs, pair touches <= 43)

// ---------------------------------------------------------------------------
// Single fused kernel. Block = 256 threads = one 32x16 output tile, 2 px per
// thread stacked in h. Input footprint staged in LDS. Per-image affine params
// recomputed per block with HW trig (v_cos/v_sin via __cosf/__sinf: ~3 instr
// each vs ~40+ for libm range-reduction) -- the uniform prologue was ~40% of
// VALU issue at R9 and VALU is the bound pipe.
// ---------------------------------------------------------------------------
__global__ __launch_bounds__(256) void affine_sample_kernel(
        const float* __restrict__ img,
        const float* __restrict__ rot,
        const float* __restrict__ trans,
        const float* __restrict__ scale,
        const float* __restrict__ shear,
        float* __restrict__ out) {
    __shared__ float tile[CHAN][BH_T][BW_T];   // 22,680 B

    const int NBLK = BATCH * (IMH / TH) * (IMW / TW);   // 128*16*8 = 16384
    const int p = blockIdx.x;
    const int L = (p & (NXCD - 1)) * (NBLK / NXCD) + (p >> 3);  // XCD-chunked

    const int b  = L >> 7;            // 128 tiles per image
    const int tl = L & 127;
    const int w0 = (tl & 7) * TW;
    const int h0 = (tl >> 3) * TH;

    // --- per-image params, block-uniform; HW trig --------------------------
    const float r   = rot[b];
    const float s   = scale[b];
    const float shx = shear[2 * b + 0];
    const float shy = shear[2 * b + 1];
    const float txr = trans[2 * b + 0];
    const float tyr = trans[2 * b + 1];
    const float c  = __cosf(r);       // v_cos_f32 (+1e-6 abs err: harmless
    const float sn = __sinf(r);       //   vs the 2e-2 tolerance)
    const float a00 = s * (c - sn * shy);
    const float a01 = s * (c * shx - sn);
    const float a10 = s * (sn + c * shy);
    const float a11 = s * (sn * shx + c);
    // linearized: ix(w,h) = Cx + a00*w + a01*h (exact; map is affine in w,h)
    const float g0x = 1.0f / (float)IMW - 1.0f;   // gx at w=0
    const float g0y = 1.0f / (float)IMH - 1.0f;   // gy at h=0
    const float Cx = ((a00 * g0x + a01 * g0y + txr + 1.0f) * (float)IMW - 1.0f) * 0.5f;
    const float Cy = ((a10 * g0x + a11 * g0y + tyr + 1.0f) * (float)IMH - 1.0f) * 0.5f;
    const float hx = 15.5f * fabsf(a00) + 7.5f * fabsf(a01);
    const float hy = 15.5f * fabsf(a10) + 7.5f * fabsf(a11);

    // --- block-uniform bbox of the input footprint -------------------------
    const float ixc = Cx + a00 * ((float)w0 + 15.5f) + a01 * ((float)h0 + 7.5f);
    const float iyc = Cy + a10 * ((float)w0 + 15.5f) + a11 * ((float)h0 + 7.5f);
    const int xlu = (int)floorf(ixc - hx);        // unclamped
    const int xhu = (int)floorf(ixc + hx) + 1;
    const int ylu = (int)floorf(iyc - hy);
    const int yhu = (int)floorf(iyc + hy) + 1;
    // all 4 taps of every pixel provably in-range
    const bool interior = (xlu >= 1) & (xhu <= IMW - 2) & (ylu >= 1) & (yhu <= IMH - 2);

    const int x_lo = min(max(xlu, 0), IMW - 1);
    const int x_hi = min(max(xhu, 0), IMW - 1);
    const int y_lo = min(max(ylu, 0), IMH - 1);
    const int y_hi = min(max(yhu, 0), IMH - 1);
    const int xs  = (x_lo - 1) & ~1;   // even staging origin (may be -2)
    const int ys  = y_lo - 1;          // staging origin      (may be -1)
    const int ncs = x_hi + 2 - xs;     // staged cols: x = xs .. x_hi+1
    const int nrs = y_hi + 2 - ys;     // staged rows: y = ys .. y_hi+1

    // --- per-thread sample coordinates: 2 px stacked in h ------------------
    const int t  = threadIdx.x;
    const int wq = w0 + (t & 31);
    const int hq = h0 + ((t >> 5) << 1);          // even row; px at hq, hq+1
    const float ixa = Cx + a00 * (float)wq + a01 * (float)hq;
    const float iya = Cy + a10 * (float)wq + a11 * (float)hq;
    const float ixb = ixa + a01;
    const float iyb = iya + a11;

    const float x0fa = floorf(ixa), y0fa = floorf(iya);
    const float x0fb = floorf(ixb), y0fb = floorf(iyb);
    const float wx1a = ixa - x0fa, wy1a = iya - y0fa;
    const float wx1b = ixb - x0fb, wy1b = iyb - y0fb;
    const float wx0a = 1.0f - wx1a, wy0a = 1.0f - wy1a;
    const float wx0b = 1.0f - wx1b, wy0b = 1.0f - wy1b;

    float w00a, w10a, w01a, w11a, w00b, w10b, w01b, w11b;
    if (interior) {                     // block-uniform branch
        w00a = wx0a * wy0a; w10a = wx1a * wy0a;
        w01a = wx0a * wy1a; w11a = wx1a * wy1a;
        w00b = wx0b * wy0b; w10b = wx1b * wy0b;
        w01b = wx0b * wy1b; w11b = wx1b * wy1b;
    } else {
        const bool vx0a = (x0fa >= 0.0f) & (x0fa <= (float)(IMW - 1));
        const bool vx1a = (x0fa >= -1.0f) & (x0fa <= (float)(IMW - 2));
        const bool vy0a = (y0fa >= 0.0f) & (y0fa <= (float)(IMH - 1));
        const bool vy1a = (y0fa >= -1.0f) & (y0fa <= (float)(IMH - 2));
        w00a = (vx0a && vy0a) ? (wx0a * wy0a) : 0.0f;
        w10a = (vx1a && vy0a) ? (wx1a * wy0a) : 0.0f;
        w01a = (vx0a && vy1a) ? (wx0a * wy1a) : 0.0f;
        w11a = (vx1a && vy1a) ? (wx1a * wy1a) : 0.0f;
        const bool vx0b = (x0fb >= 0.0f) & (x0fb <= (float)(IMW - 1));
        const bool vx1b = (x0fb >= -1.0f) & (x0fb <= (float)(IMW - 2));
        const bool vy0b = (y0fb >= 0.0f) & (y0fb <= (float)(IMH - 1));
        const bool vy1b = (y0fb >= -1.0f) & (y0fb <= (float)(IMH - 2));
        w00b = (vx0b && vy0b) ? (wx0b * wy0b) : 0.0f;
        w10b = (vx1b && vy0b) ? (wx1b * wy0b) : 0.0f;
        w01b = (vx0b && vy1b) ? (wx0b * wy1b) : 0.0f;
        w11b = (vx1b && vy1b) ? (wx1b * wy1b) : 0.0f;
    }

    const int x0ia = (int)x0fa, y0ia = (int)y0fa;
    const int x0ib = (int)x0fb, y0ib = (int)y0fb;

    const int plane = IMH * IMW;
    const int obase = (b * CHAN) * plane + hq * IMW + wq;
    const float* ibase = img + (size_t)(b * CHAN) * plane;

    // --- staged path iff footprint fits LDS. Block-uniform branch. ---------
    if (ncs <= NC_MAX && nrs <= BH_T) {
        // Stager: 32 float2-lanes (64 cols) x 8 rows per round; channel-inner.
        // No zero-fill: addresses clamped into the image; any tap that could
        // read a garbage cell has weight exactly 0 (reference semantics).
        const int lx2 = (t & 31) << 1;            // 0,2,..,62
        const int lyr = t >> 5;                   // 0..7
        const int nrd = (nrs + 7) >> 3;           // 1..6 row rounds
        const bool wcol = lx2 < ncs;
        const int xg = min(max(xs + lx2, 0), IMW - 2);   // even
        for (int rr = 0; rr < nrd; ++rr) {
            const int dy = (rr << 3) + lyr;
            if (wcol & (dy < nrs)) {
                const int yg = min(max(ys + dy, 0), IMH - 1);
                const float* src = ibase + yg * IMW + xg;
                const float2 v0 = *(const float2*)(src);
                const float2 v1 = *(const float2*)(src + plane);
                const float2 v2 = *(const float2*)(src + 2 * plane);
                tile[0][dy][lx2]     = v0.x;
                tile[0][dy][lx2 + 1] = v0.y;
                tile[1][dy][lx2]     = v1.x;
                tile[1][dy][lx2 + 1] = v1.y;
                tile[2][dy][lx2]     = v2.x;
                tile[2][dy][lx2 + 1] = v2.y;
            }
        }
        __syncthreads();

        // Gather from LDS. Interior: unclamped (halo + bbox proof covers it).
        // Border blocks: clamp into the written region so zero-weight taps
        // read staged (finite) cells, never uninitialized LDS.
        int rxa, rya, rxb, ryb;
        if (interior) {
            rxa = x0ia - xs;  rya = y0ia - ys;
            rxb = x0ib - xs;  ryb = y0ib - ys;
        } else {
            rxa = min(max(x0ia - xs, 0), ncs - 2);
            rya = min(max(y0ia - ys, 0), nrs - 2);
            rxb = min(max(x0ib - xs, 0), ncs - 2);
            ryb = min(max(y0ib - ys, 0), nrs - 2);
        }
#pragma unroll
        for (int cc = 0; cc < CHAN; ++cc) {
            const float* tpa = &tile[cc][rya][rxa];
            const float* tpb = &tile[cc][ryb][rxb];
            const float va = w00a * tpa[0] + w10a * tpa[1]
                           + w01a * tpa[BW_T] + w11a * tpa[BW_T + 1];
            const float vb = w00b * tpb[0] + w10b * tpb[1]
                           + w01b * tpb[BW_T] + w11b * tpb[BW_T + 1];
            out[obase + cc * plane]       = va;
            out[obase + cc * plane + IMW] = vb;
        }
    } else {
        // fallback: direct global gathers (extreme shear/rotation tail only)
        const int x0ca = min(max(x0ia, 0), IMW - 1);
        const int x1ca = min(max(x0ia + 1, 0), IMW - 1);
        const int y0ca = min(max(y0ia, 0), IMH - 1);
        const int y1ca = min(max(y0ia + 1, 0), IMH - 1);
        const int x0cb = min(max(x0ib, 0), IMW - 1);
        const int x1cb = min(max(x0ib + 1, 0), IMW - 1);
        const int y0cb = min(max(y0ib, 0), IMH - 1);
        const int y1cb = min(max(y0ib + 1, 0), IMH - 1);
#pragma unroll
        for (int cc = 0; cc < CHAN; ++cc) {
            const float* p2 = ibase + cc * plane;
            const float va = w00a * p2[y0ca * IMW + x0ca] + w10a * p2[y0ca * IMW + x1ca]
                           + w01a * p2[y1ca * IMW + x0ca] + w11a * p2[y1ca * IMW + x1ca];
            const float vb = w00b * p2[y0cb * IMW + x0cb] + w10b * p2[y0cb * IMW + x1cb]
                           + w01b * p2[y1cb * IMW + x0cb] + w11b * p2[y1cb * IMW + x1cb];
            out[obase + cc * plane]       = va;
            out[obase + cc * plane + IMW] = vb;
        }
    }
}

extern "C" void kernel_launch(void* const* d_in, const int* in_sizes, int n_in,
                              void* d_out, int out_size, void* d_ws, size_t ws_size,
                              hipStream_t stream) {
    const float* img   = (const float*)d_in[0];
    const float* rot   = (const float*)d_in[1];
    const float* trans = (const float*)d_in[2];
    const float* scale = (const float*)d_in[3];
    const float* shear = (const float*)d_in[4];
    float* out = (float*)d_out;

    const int nblocks = BATCH * (IMH / TH) * (IMW / TW);   // 16384
    affine_sample_kernel<<<nblocks, 256, 0, stream>>>(img, rot, trans, scale,
                                                      shear, out);
}